// Round 14
// baseline (171.363 us; speedup 1.0000x reference)
//
#include <hip/hip_runtime.h>
#include <cstdint>

#define ZFULL 136
#define NCTX 16
#define KCLS 75

typedef __bf16 bf16x8 __attribute__((ext_vector_type(8)));
typedef float f32x4 __attribute__((ext_vector_type(4)));

__device__ __forceinline__ ushort bf16_rne(float v) {
  uint32_t u = __float_as_uint(v);
  return (ushort)((u + 0x7fffu + ((u >> 16) & 1u)) >> 16);
}

__device__ __forceinline__ float rdlane(float v, int l) {
  return __int_as_float(__builtin_amdgcn_readlane(__float_as_int(v), l));
}

__device__ __forceinline__ float bperm(float v, int srcLane) {
  return __int_as_float(__builtin_amdgcn_ds_bpermute(srcLane * 4, __float_as_int(v)));
}

// packed bf16 convert (RNE), no builtin on gfx950 -> inline asm
__device__ __forceinline__ uint32_t cvt_pk_bf16(float lo, float hi) {
  uint32_t d;
  asm("v_cvt_pk_bf16_f32 %0, %1, %2" : "=v"(d) : "v"(lo), "v"(hi));
  return d;
}

// ---- pack A: [CH/16 m_tiles][5 k_tiles][2 h][64 lane][8 j] ushorts (bf16) ----
__global__ __launch_bounds__(256) void pack_A(const float* __restrict__ z,
                                              const int* __restrict__ labels,
                                              ushort* __restrict__ Apk,
                                              int b0, int CH) {
  int idx = blockIdx.x * 256 + threadIdx.x;  // (mt,kt,h,lane)
  int lane = idx & 63;
  int h = (idx >> 6) & 1;
  int kt = (idx >> 7) % 5;
  int mt = idx / 640;
  if (mt >= CH / 16) return;
  int m = b0 + mt * 16 + (lane & 15);
  int kbase = kt * 32 + (lane >> 4) * 8;
  ushort o[8];
#pragma unroll
  for (int j = 0; j < 8; ++j) {
    int k = kbase + j;
    float v = 0.0f;
    if (k < ZFULL) v = z[(size_t)m * ZFULL + k];
    else if (k < ZFULL + NCTX) v = (float)labels[(size_t)m * NCTX + (k - ZFULL)];
    ushort hi = bf16_rne(v);
    if (h == 0) o[j] = hi;
    else {
      float fhi = __uint_as_float((uint32_t)hi << 16);
      o[j] = bf16_rne(v - fhi);
    }
  }
  uint4 w;
  w.x = (uint32_t)o[0] | ((uint32_t)o[1] << 16);
  w.y = (uint32_t)o[2] | ((uint32_t)o[3] << 16);
  w.z = (uint32_t)o[4] | ((uint32_t)o[5] << 16);
  w.w = (uint32_t)o[6] | ((uint32_t)o[7] << 16);
  *(uint4*)(Apk + (size_t)idx * 8) = w;
}

// ---- pack B: [256 n_tiles][5 k_tiles][2 h][64 lane][8 j] ushorts (bf16) ----
__global__ __launch_bounds__(256) void pack_B(const float* __restrict__ Kp,
                                              const float* __restrict__ Lm,
                                              ushort* __restrict__ Bpk) {
  int idx = blockIdx.x * 256 + threadIdx.x;
  int lane = idx & 63;
  int h = (idx >> 6) & 1;
  int kt = (idx >> 7) % 5;
  int nt = idx / 640;
  if (nt >= 256) return;
  int n = nt * 16 + (lane & 15);
  int kbase = kt * 32 + (lane >> 4) * 8;
  ushort o[8];
#pragma unroll
  for (int j = 0; j < 8; ++j) {
    int k = kbase + j;
    float v = 0.0f;
    if (k < ZFULL) v = Kp[(size_t)n * ZFULL + k];
    else if (k < ZFULL + NCTX) v = Lm[(size_t)n * NCTX + (k - ZFULL)];
    ushort hi = bf16_rne(v);
    if (h == 0) o[j] = hi;
    else {
      float fhi = __uint_as_float((uint32_t)hi << 16);
      o[j] = bf16_rne(v - fhi);
    }
  }
  uint4 w;
  w.x = (uint32_t)o[0] | ((uint32_t)o[1] << 16);
  w.y = (uint32_t)o[2] | ((uint32_t)o[3] << 16);
  w.z = (uint32_t)o[4] | ((uint32_t)o[5] << 16);
  w.w = (uint32_t)o[6] | ((uint32_t)o[7] << 16);
  *(uint4*)(Bpk + (size_t)idx * 8) = w;
}

// ---- 2-term split-bf16 MFMA GEMM -> bf16 rates ----
// C ~= Ah*(Bh+Bl): dropped Al*Bh correction (error ~2^-9 rel on log-rates,
// ~0.1% on rates; logits delta << 0.46 threshold). 160 MFMA + 40 A-loads
// per wave vs 240 + 80.
__global__ __launch_bounds__(256) void gemm_mfma(const ushort* __restrict__ Apk,
                                                 const ushort* __restrict__ Bpk,
                                                 const float* __restrict__ base_log,
                                                 ushort* __restrict__ rates) {
  const int tid = threadIdx.x;
  const int lane = tid & 63;
  const int w = tid >> 6;
  const int wm = w & 1, wn = w >> 1;
  const int m_tile0 = blockIdx.x * 8 + wm * 4;
  const int n_tile0 = blockIdx.y * 8 + wn * 4;

  f32x4 acc[4][4] = {};

#pragma unroll
  for (int kt = 0; kt < 5; ++kt) {
    bf16x8 ah[4], bh[4], bl[4];
#pragma unroll
    for (int mt = 0; mt < 4; ++mt) {
      size_t off = (((size_t)(m_tile0 + mt) * 5 + kt) * 128 + lane) * 8;
      ah[mt] = *(const bf16x8*)(Apk + off);
    }
#pragma unroll
    for (int nt = 0; nt < 4; ++nt) {
      size_t off = (((size_t)(n_tile0 + nt) * 5 + kt) * 128 + lane) * 8;
      bh[nt] = *(const bf16x8*)(Bpk + off);
      bl[nt] = *(const bf16x8*)(Bpk + off + 512);
    }
#pragma unroll
    for (int mt = 0; mt < 4; ++mt)
#pragma unroll
      for (int nt = 0; nt < 4; ++nt) {
        acc[mt][nt] = __builtin_amdgcn_mfma_f32_16x16x32_bf16(ah[mt], bh[nt], acc[mt][nt], 0, 0, 0);
        acc[mt][nt] = __builtin_amdgcn_mfma_f32_16x16x32_bf16(ah[mt], bl[nt], acc[mt][nt], 0, 0, 0);
      }
  }

  const int col_l = lane & 15;
  const int row_l = (lane >> 4) * 4;
  const bool evenc = (col_l & 1) == 0;
#pragma unroll
  for (int mt = 0; mt < 4; ++mt) {
#pragma unroll
    for (int nt = 0; nt < 4; ++nt) {
      int n = (n_tile0 + nt) * 16 + col_l;
      int i = n >> 6, j = n & 63;
      float bse = base_log[n];
      float x[4], y[4];
#pragma unroll
      for (int r = 0; r < 4; ++r) {
        float v = acc[mt][nt][r] + bse;
        v = fminf(fmaxf(v, -15.0f), 3.0f);
        float e = __expf(v);
        x[r] = (i == j) ? 0.0f : e;
      }
      // static-index exchanges: both lanes of the pair contribute row r in the
      // same instruction (round-13 version had lane-dependent r -> fragile).
#pragma unroll
      for (int r = 0; r < 4; ++r) y[r] = __shfl_xor(x[r], 1);
      // even col lane stores rows 0,1; odd col lane stores rows 2,3
#pragma unroll
      for (int rr = 0; rr < 2; ++rr) {
        int r = evenc ? rr : 2 + rr;
        float lo = evenc ? x[r] : y[r];
        float hi = evenc ? y[r] : x[r];
        uint32_t dw = cvt_pk_bf16(lo, hi);
        int m = (m_tile0 + mt) * 16 + row_l + r;
        *(uint32_t*)(rates + (size_t)m * 4096 + (n & ~1)) = dw;
      }
    }
  }
}

// ===== row-layout Gauss-Jordan; broadcasts split across VALU (readlane)
// and LDS (bpermute) pipes — r11/r12 showed either alone saturates at ~85us;
// if single-pipe-throughput-bound, 50/50 split should give up to ~1.5x. =====
template <int K>
struct GJ {
  static __device__ __forceinline__ void run(float (&a)[64], float& d, int lane) {
    float piv = rdlane(a[K], K);
    float rp = __builtin_amdgcn_rcpf(piv);
    bool isk = (lane == K);
    float m = isk ? 0.0f : a[K] * rp;
    d = isk ? piv : d;
#pragma unroll
    for (int j = K + 1; j < 64; ++j) {
      float p = (((j ^ K) & 1) != 0) ? bperm(a[j], K) : rdlane(a[j], K);
      a[j] = fmaf(-m, p, a[j]);
    }
    GJ<K + 1>::run(a, d, lane);
  }
};
template <>
struct GJ<63> {
  static __device__ __forceinline__ void run(float (&)[64], float&, int) {}
};

// ---- solve + attention + logits: one wave per batch (bf16 rates input) ----
__global__ __launch_bounds__(256) void solve_kernel(const ushort* __restrict__ rates,
                                                    const int* __restrict__ labels,
                                                    const float* __restrict__ Bm,
                                                    float* __restrict__ out,
                                                    int b0) {
  __shared__ float Blds[64][16];
  __shared__ float xbuf[4][64];
  __shared__ float att_lds[4][16];
  __shared__ float acc[4][80];

  const int tid = threadIdx.x;
  for (int idx = tid; idx < 1024; idx += 256)
    Blds[idx >> 4][idx & 15] = Bm[idx];

  const int wave = tid >> 6;
  const int lane = tid & 63;
  const int batch = b0 + blockIdx.x * 4 + wave;
  const ushort* Rb = rates + (size_t)(blockIdx.x * 4 + wave) * 4096;

  // ---- pass 1: cs = colsum of column `lane` (diag entries are 0) ----
  float cs = 0.0f;
#pragma unroll
  for (int i = 0; i < 64; ++i)
    cs += __uint_as_float((uint32_t)Rb[i * 64 + lane] << 16);

  // ---- pass 2: lane holds ROW `lane`: a[j] = rates[lane][j] (L1/L2 hot) ----
  const ushort* R = Rb + (size_t)lane * 64;
  float a[64];
#pragma unroll
  for (int q = 0; q < 8; ++q) {
    uint4 u = *(const uint4*)(R + q * 8);
    uint32_t ww[4] = {u.x, u.y, u.z, u.w};
#pragma unroll
    for (int t = 0; t < 4; ++t) {
      a[q * 8 + t * 2 + 0] = __uint_as_float(ww[t] << 16);
      a[q * 8 + t * 2 + 1] = __uint_as_float(ww[t] & 0xFFFF0000u);
    }
  }

  // ---- build K_mod: diag = -colsum (rows 0..62); row 63 = all ones ----
  const bool is63 = (lane == 63);
  const float ncs = -cs;
#pragma unroll
  for (int j = 0; j < 64; ++j) {
    float v = (lane == j) ? ncs : a[j];
    a[j] = is63 ? 1.0f : v;
  }

  // ---- Gauss-Jordan pivots 0..62 (no pivoting; col-diag-dominant). b=e63 untouched. ----
  float d = 1.0f;
  GJ<0>::run(a, d, lane);

  // row i<63:  d_i*x_i + a[63]*x63 = 0 ;  row 63: a[63]*x63 = 1
  float m6363 = rdlane(a[63], 63);
  float x63 = 1.0f / m6363;
  float x = is63 ? x63 : -a[63] * x63 * __builtin_amdgcn_rcpf(d);

  // clip >= 0 and normalize
  x = fmaxf(x, 0.0f);
  float s = x;
  s += __shfl_xor(s, 32); s += __shfl_xor(s, 16); s += __shfl_xor(s, 8);
  s += __shfl_xor(s, 4);  s += __shfl_xor(s, 2);  s += __shfl_xor(s, 1);
  x = x / s;

  xbuf[wave][lane] = x;
  if (lane < 16) {
    acc[wave][lane] = 1e-10f;
    acc[wave][16 + lane] = 1e-10f;
    acc[wave][32 + lane] = 1e-10f;
    acc[wave][48 + lane] = 1e-10f;
    acc[wave][64 + lane] = 1e-10f;
  }
  __syncthreads();

  // q[t] = p . B[:,t] for t = lane < 16
  float q = 0.0f;
  if (lane < 16) {
#pragma unroll 8
    for (int n = 0; n < 64; ++n) q = fmaf(xbuf[wave][n], Blds[n][lane], q);
  }
  float qm = q;
  qm = fmaxf(qm, __shfl_xor(qm, 8)); qm = fmaxf(qm, __shfl_xor(qm, 4));
  qm = fmaxf(qm, __shfl_xor(qm, 2)); qm = fmaxf(qm, __shfl_xor(qm, 1));
  float e = expf(q - qm);
  float es = e;
  es += __shfl_xor(es, 8); es += __shfl_xor(es, 4);
  es += __shfl_xor(es, 2); es += __shfl_xor(es, 1);
  if (lane < 16) att_lds[wave][lane] = e / es;
  __syncthreads();

  // deterministic serial bucket-accumulate (no atomics)
  if (lane == 0) {
#pragma unroll
    for (int n = 0; n < 16; ++n) {
      int lb = labels[(size_t)batch * 16 + n];
      acc[wave][lb - 1] += att_lds[wave][n];
    }
  }
  __syncthreads();

  float* ob = out + (size_t)batch * 75;
  ob[lane] = logf(acc[wave][lane]);
  if (lane < 11) ob[64 + lane] = logf(acc[wave][64 + lane]);
}

extern "C" void kernel_launch(void* const* d_in, const int* in_sizes, int n_in,
                              void* d_out, int out_size, void* d_ws, size_t ws_size,
                              hipStream_t stream) {
  const float* z      = (const float*)d_in[0];
  const int*   labels = (const int*)d_in[1];
  const float* Kp     = (const float*)d_in[2];
  const float* Lm     = (const float*)d_in[3];
  const float* Bm     = (const float*)d_in[4];
  const float* base   = (const float*)d_in[5];
  float* out = (float*)d_out;

  const int bsz = in_sizes[0] / ZFULL;  // 8192

  const size_t B_bytes = (size_t)256 * 5 * 2 * 64 * 8 * sizeof(ushort);  // 2.62 MB
  int CH = bsz;
  while (CH > 128) {
    size_t A_bytes = (size_t)(CH / 16) * 5 * 2 * 64 * 8 * sizeof(ushort);
    size_t need = B_bytes + A_bytes + (size_t)CH * 4096 * sizeof(ushort);
    if (need <= ws_size) break;
    CH >>= 1;
  }
  ushort* Bpk = (ushort*)d_ws;
  ushort* Apk = (ushort*)((char*)d_ws + B_bytes);
  size_t A_bytes = (size_t)(CH / 16) * 5 * 2 * 64 * 8 * sizeof(ushort);
  ushort* rates = (ushort*)((char*)d_ws + B_bytes + A_bytes);

  pack_B<<<(256 * 640 + 255) / 256, 256, 0, stream>>>(Kp, Lm, Bpk);

  for (int b0 = 0; b0 < bsz; b0 += CH) {
    int a_threads = (CH / 16) * 640;
    pack_A<<<(a_threads + 255) / 256, 256, 0, stream>>>(z, labels, Apk, b0, CH);
    dim3 g(CH / 128, 32);
    gemm_mfma<<<g, 256, 0, stream>>>(Apk, Bpk, base, rates);
    solve_kernel<<<CH / 4, 256, 0, stream>>>(rates, labels, Bm, out, b0);
  }
}

// Round 15
// 138.930 us; speedup vs baseline: 1.2334x; 1.2334x over previous
//
#include <hip/hip_runtime.h>
#include <cstdint>

#define ZFULL 136
#define NCTX 16
#define KCLS 75

typedef __bf16 bf16x8 __attribute__((ext_vector_type(8)));
typedef float f32x4 __attribute__((ext_vector_type(4)));

__device__ __forceinline__ ushort bf16_rne(float v) {
  uint32_t u = __float_as_uint(v);
  return (ushort)((u + 0x7fffu + ((u >> 16) & 1u)) >> 16);
}

__device__ __forceinline__ float rdlane(float v, int l) {
  return __int_as_float(__builtin_amdgcn_readlane(__float_as_int(v), l));
}

__device__ __forceinline__ float bperm(float v, int srcLane) {
  return __int_as_float(__builtin_amdgcn_ds_bpermute(srcLane * 4, __float_as_int(v)));
}

// packed bf16 convert: dword = (bf16(lo) | bf16(hi)<<16), RNE. No builtin on
// gfx950 -> inline asm.
__device__ __forceinline__ uint32_t cvt_pk_bf16(float lo, float hi) {
  uint32_t d;
  asm("v_cvt_pk_bf16_f32 %0, %1, %2" : "=v"(d) : "v"(lo), "v"(hi));
  return d;
}

// ---- pack A: [CH/16 m_tiles][5 k_tiles][2 h][64 lane][8 j] ushorts (bf16) ----
__global__ __launch_bounds__(256) void pack_A(const float* __restrict__ z,
                                              const int* __restrict__ labels,
                                              ushort* __restrict__ Apk,
                                              int b0, int CH) {
  int idx = blockIdx.x * 256 + threadIdx.x;  // (mt,kt,h,lane)
  int lane = idx & 63;
  int h = (idx >> 6) & 1;
  int kt = (idx >> 7) % 5;
  int mt = idx / 640;
  if (mt >= CH / 16) return;
  int m = b0 + mt * 16 + (lane & 15);
  int kbase = kt * 32 + (lane >> 4) * 8;
  ushort o[8];
#pragma unroll
  for (int j = 0; j < 8; ++j) {
    int k = kbase + j;
    float v = 0.0f;
    if (k < ZFULL) v = z[(size_t)m * ZFULL + k];
    else if (k < ZFULL + NCTX) v = (float)labels[(size_t)m * NCTX + (k - ZFULL)];
    ushort hi = bf16_rne(v);
    if (h == 0) o[j] = hi;
    else {
      float fhi = __uint_as_float((uint32_t)hi << 16);
      o[j] = bf16_rne(v - fhi);
    }
  }
  uint4 w;
  w.x = (uint32_t)o[0] | ((uint32_t)o[1] << 16);
  w.y = (uint32_t)o[2] | ((uint32_t)o[3] << 16);
  w.z = (uint32_t)o[4] | ((uint32_t)o[5] << 16);
  w.w = (uint32_t)o[6] | ((uint32_t)o[7] << 16);
  *(uint4*)(Apk + (size_t)idx * 8) = w;
}

// ---- pack B: [256 n_tiles][5 k_tiles][2 h][64 lane][8 j] ushorts (bf16) ----
__global__ __launch_bounds__(256) void pack_B(const float* __restrict__ Kp,
                                              const float* __restrict__ Lm,
                                              ushort* __restrict__ Bpk) {
  int idx = blockIdx.x * 256 + threadIdx.x;
  int lane = idx & 63;
  int h = (idx >> 6) & 1;
  int kt = (idx >> 7) % 5;
  int nt = idx / 640;
  if (nt >= 256) return;
  int n = nt * 16 + (lane & 15);
  int kbase = kt * 32 + (lane >> 4) * 8;
  ushort o[8];
#pragma unroll
  for (int j = 0; j < 8; ++j) {
    int k = kbase + j;
    float v = 0.0f;
    if (k < ZFULL) v = Kp[(size_t)n * ZFULL + k];
    else if (k < ZFULL + NCTX) v = Lm[(size_t)n * NCTX + (k - ZFULL)];
    ushort hi = bf16_rne(v);
    if (h == 0) o[j] = hi;
    else {
      float fhi = __uint_as_float((uint32_t)hi << 16);
      o[j] = bf16_rne(v - fhi);
    }
  }
  uint4 w;
  w.x = (uint32_t)o[0] | ((uint32_t)o[1] << 16);
  w.y = (uint32_t)o[2] | ((uint32_t)o[3] << 16);
  w.z = (uint32_t)o[4] | ((uint32_t)o[5] << 16);
  w.w = (uint32_t)o[6] | ((uint32_t)o[7] << 16);
  *(uint4*)(Bpk + (size_t)idx * 8) = w;
}

// ---- split-bf16 MFMA GEMM -> bf16 rates ----
// Epilogue: __expf + lane-pair exchange + v_cvt_pk_bf16_f32 + dword stores
__global__ __launch_bounds__(256) void gemm_mfma(const ushort* __restrict__ Apk,
                                                 const ushort* __restrict__ Bpk,
                                                 const float* __restrict__ base_log,
                                                 ushort* __restrict__ rates) {
  const int tid = threadIdx.x;
  const int lane = tid & 63;
  const int w = tid >> 6;
  const int wm = w & 1, wn = w >> 1;
  const int m_tile0 = blockIdx.x * 8 + wm * 4;
  const int n_tile0 = blockIdx.y * 8 + wn * 4;

  f32x4 acc[4][4] = {};

#pragma unroll
  for (int kt = 0; kt < 5; ++kt) {
    bf16x8 ah[4], al[4], bh[4], bl[4];
#pragma unroll
    for (int mt = 0; mt < 4; ++mt) {
      size_t off = (((size_t)(m_tile0 + mt) * 5 + kt) * 128 + lane) * 8;
      ah[mt] = *(const bf16x8*)(Apk + off);
      al[mt] = *(const bf16x8*)(Apk + off + 512);
    }
#pragma unroll
    for (int nt = 0; nt < 4; ++nt) {
      size_t off = (((size_t)(n_tile0 + nt) * 5 + kt) * 128 + lane) * 8;
      bh[nt] = *(const bf16x8*)(Bpk + off);
      bl[nt] = *(const bf16x8*)(Bpk + off + 512);
    }
#pragma unroll
    for (int mt = 0; mt < 4; ++mt)
#pragma unroll
      for (int nt = 0; nt < 4; ++nt) {
        acc[mt][nt] = __builtin_amdgcn_mfma_f32_16x16x32_bf16(ah[mt], bh[nt], acc[mt][nt], 0, 0, 0);
        acc[mt][nt] = __builtin_amdgcn_mfma_f32_16x16x32_bf16(ah[mt], bl[nt], acc[mt][nt], 0, 0, 0);
        acc[mt][nt] = __builtin_amdgcn_mfma_f32_16x16x32_bf16(al[mt], bh[nt], acc[mt][nt], 0, 0, 0);
      }
  }

  const int col_l = lane & 15;
  const int row_l = (lane >> 4) * 4;
  const bool evenc = (col_l & 1) == 0;
  const int r0 = evenc ? 0 : 2;  // even cols store rows r=0,1; odd cols r=2,3
#pragma unroll
  for (int mt = 0; mt < 4; ++mt) {
#pragma unroll
    for (int nt = 0; nt < 4; ++nt) {
      int n = (n_tile0 + nt) * 16 + col_l;
      int i = n >> 6, j = n & 63;
      float bse = base_log[n];
      float x[4];
#pragma unroll
      for (int r = 0; r < 4; ++r) {
        float v = acc[mt][nt][r] + bse;
        v = fminf(fmaxf(v, -15.0f), 3.0f);
        float e = __expf(v);
        x[r] = (i == j) ? 0.0f : e;
      }
#pragma unroll
      for (int rr = 0; rr < 2; ++rr) {
        int r = r0 + rr;
        float y = __shfl_xor(x[r], 1);  // partner holds col n^1
        float lo = evenc ? x[r] : y;
        float hi = evenc ? y : x[r];
        uint32_t dw = cvt_pk_bf16(lo, hi);
        int m = (m_tile0 + mt) * 16 + row_l + r;
        *(uint32_t*)(rates + (size_t)m * 4096 + (n & ~1)) = dw;
      }
#pragma unroll
      for (int rr = 0; rr < 2; ++rr) {
        int r = (r0 ^ 2) + rr;
        float y = __shfl_xor(x[r], 1);
        (void)y;
      }
    }
  }
}

// ===== row-layout Gauss-Jordan: lane = row; pivot-row broadcast via bpermute =====
template <int K>
struct GJ {
  static __device__ __forceinline__ void run(float (&a)[64], float& d, int lane) {
    float piv = bperm(a[K], K);
    float rp = __builtin_amdgcn_rcpf(piv);
    bool isk = (lane == K);
    float m = isk ? 0.0f : a[K] * rp;
    d = isk ? piv : d;
#pragma unroll
    for (int j = K + 1; j < 64; ++j) {
      float p = bperm(a[j], K);
      a[j] = fmaf(-m, p, a[j]);
    }
    GJ<K + 1>::run(a, d, lane);
  }
};
template <>
struct GJ<63> {
  static __device__ __forceinline__ void run(float (&)[64], float&, int) {}
};

// ---- solve + attention + logits: one wave per batch (bf16 rates input) ----
__global__ __launch_bounds__(256) void solve_kernel(const ushort* __restrict__ rates,
                                                    const int* __restrict__ labels,
                                                    const float* __restrict__ Bm,
                                                    float* __restrict__ out,
                                                    int b0) {
  __shared__ float Blds[64][16];
  __shared__ float xbuf[4][64];
  __shared__ float att_lds[4][16];
  __shared__ float acc[4][80];

  const int tid = threadIdx.x;
  for (int idx = tid; idx < 1024; idx += 256)
    Blds[idx >> 4][idx & 15] = Bm[idx];

  const int wave = tid >> 6;
  const int lane = tid & 63;
  const int batch = b0 + blockIdx.x * 4 + wave;
  const ushort* Rb = rates + (size_t)(blockIdx.x * 4 + wave) * 4096;

  // ---- pass 1: cs = colsum of column `lane` (diag entries are 0) ----
  float cs = 0.0f;
#pragma unroll
  for (int i = 0; i < 64; ++i)
    cs += __uint_as_float((uint32_t)Rb[i * 64 + lane] << 16);

  // ---- pass 2: lane holds ROW `lane`: a[j] = rates[lane][j] (L1/L2 hot) ----
  const ushort* R = Rb + (size_t)lane * 64;
  float a[64];
#pragma unroll
  for (int q = 0; q < 8; ++q) {
    uint4 u = *(const uint4*)(R + q * 8);
    uint32_t ww[4] = {u.x, u.y, u.z, u.w};
#pragma unroll
    for (int t = 0; t < 4; ++t) {
      a[q * 8 + t * 2 + 0] = __uint_as_float(ww[t] << 16);
      a[q * 8 + t * 2 + 1] = __uint_as_float(ww[t] & 0xFFFF0000u);
    }
  }

  // ---- build K_mod: diag = -colsum (rows 0..62); row 63 = all ones ----
  const bool is63 = (lane == 63);
  const float ncs = -cs;
#pragma unroll
  for (int j = 0; j < 64; ++j) {
    float v = (lane == j) ? ncs : a[j];
    a[j] = is63 ? 1.0f : v;
  }

  // ---- Gauss-Jordan pivots 0..62 (no pivoting; col-diag-dominant). b=e63 untouched. ----
  float d = 1.0f;
  GJ<0>::run(a, d, lane);

  // row i<63:  d_i*x_i + a[63]*x63 = 0 ;  row 63: a[63]*x63 = 1
  float m6363 = rdlane(a[63], 63);
  float x63 = 1.0f / m6363;
  float x = is63 ? x63 : -a[63] * x63 * __builtin_amdgcn_rcpf(d);

  // clip >= 0 and normalize
  x = fmaxf(x, 0.0f);
  float s = x;
  s += __shfl_xor(s, 32); s += __shfl_xor(s, 16); s += __shfl_xor(s, 8);
  s += __shfl_xor(s, 4);  s += __shfl_xor(s, 2);  s += __shfl_xor(s, 1);
  x = x / s;

  xbuf[wave][lane] = x;
  if (lane < 16) {
    acc[wave][lane] = 1e-10f;
    acc[wave][16 + lane] = 1e-10f;
    acc[wave][32 + lane] = 1e-10f;
    acc[wave][48 + lane] = 1e-10f;
    acc[wave][64 + lane] = 1e-10f;
  }
  __syncthreads();

  // q[t] = p . B[:,t] for t = lane < 16
  float q = 0.0f;
  if (lane < 16) {
#pragma unroll 8
    for (int n = 0; n < 64; ++n) q = fmaf(xbuf[wave][n], Blds[n][lane], q);
  }
  float qm = q;
  qm = fmaxf(qm, __shfl_xor(qm, 8)); qm = fmaxf(qm, __shfl_xor(qm, 4));
  qm = fmaxf(qm, __shfl_xor(qm, 2)); qm = fmaxf(qm, __shfl_xor(qm, 1));
  float e = expf(q - qm);
  float es = e;
  es += __shfl_xor(es, 8); es += __shfl_xor(es, 4);
  es += __shfl_xor(es, 2); es += __shfl_xor(es, 1);
  if (lane < 16) att_lds[wave][lane] = e / es;
  __syncthreads();

  // deterministic serial bucket-accumulate (no atomics)
  if (lane == 0) {
#pragma unroll
    for (int n = 0; n < 16; ++n) {
      int lb = labels[(size_t)batch * 16 + n];
      acc[wave][lb - 1] += att_lds[wave][n];
    }
  }
  __syncthreads();

  float* ob = out + (size_t)batch * 75;
  ob[lane] = logf(acc[wave][lane]);
  if (lane < 11) ob[64 + lane] = logf(acc[wave][64 + lane]);
}

extern "C" void kernel_launch(void* const* d_in, const int* in_sizes, int n_in,
                              void* d_out, int out_size, void* d_ws, size_t ws_size,
                              hipStream_t stream) {
  const float* z      = (const float*)d_in[0];
  const int*   labels = (const int*)d_in[1];
  const float* Kp     = (const float*)d_in[2];
  const float* Lm     = (const float*)d_in[3];
  const float* Bm     = (const float*)d_in[4];
  const float* base   = (const float*)d_in[5];
  float* out = (float*)d_out;

  const int bsz = in_sizes[0] / ZFULL;  // 8192

  const size_t B_bytes = (size_t)256 * 5 * 2 * 64 * 8 * sizeof(ushort);  // 2.62 MB
  int CH = bsz;
  while (CH > 128) {
    size_t A_bytes = (size_t)(CH / 16) * 5 * 2 * 64 * 8 * sizeof(ushort);
    size_t need = B_bytes + A_bytes + (size_t)CH * 4096 * sizeof(ushort);
    if (need <= ws_size) break;
    CH >>= 1;
  }
  ushort* Bpk = (ushort*)d_ws;
  ushort* Apk = (ushort*)((char*)d_ws + B_bytes);
  size_t A_bytes = (size_t)(CH / 16) * 5 * 2 * 64 * 8 * sizeof(ushort);
  ushort* rates = (ushort*)((char*)d_ws + B_bytes + A_bytes);

  pack_B<<<(256 * 640 + 255) / 256, 256, 0, stream>>>(Kp, Lm, Bpk);

  for (int b0 = 0; b0 < bsz; b0 += CH) {
    int a_threads = (CH / 16) * 640;
    pack_A<<<(a_threads + 255) / 256, 256, 0, stream>>>(z, labels, Apk, b0, CH);
    dim3 g(CH / 128, 32);
    gemm_mfma<<<g, 256, 0, stream>>>(Apk, Bpk, base, rates);
    solve_kernel<<<CH / 4, 256, 0, stream>>>(rates, labels, Bm, out, b0);
  }
}

// Round 17
// 112.721 us; speedup vs baseline: 1.5202x; 1.2325x over previous
//
#include <hip/hip_runtime.h>
#include <cstdint>

#define ZFULL 136
#define NCTX 16
#define KCLS 75

typedef __bf16 bf16x8 __attribute__((ext_vector_type(8)));
typedef float f32x4 __attribute__((ext_vector_type(4)));
typedef _Float16 f16x2 __attribute__((ext_vector_type(2)));

__device__ __forceinline__ ushort bf16_rne(float v) {
  uint32_t u = __float_as_uint(v);
  return (ushort)((u + 0x7fffu + ((u >> 16) & 1u)) >> 16);
}

__device__ __forceinline__ float rdlane(float v, int l) {
  return __int_as_float(__builtin_amdgcn_readlane(__float_as_int(v), l));
}

__device__ __forceinline__ f16x2 bperm_h2(f16x2 v, int srcLane) {
  int i;
  __builtin_memcpy(&i, &v, 4);
  i = __builtin_amdgcn_ds_bpermute(srcLane * 4, i);
  f16x2 r;
  __builtin_memcpy(&r, &i, 4);
  return r;
}

// v_cvt_pkrtz_f16_f32 returns __fp16 vec2; bitcast to our _Float16 vec2
__device__ __forceinline__ f16x2 pkrtz(float lo, float hi) {
  auto t = __builtin_amdgcn_cvt_pkrtz(lo, hi);
  f16x2 r;
  __builtin_memcpy(&r, &t, 4);
  return r;
}

// packed bf16 convert (RNE), no builtin on gfx950 -> inline asm
__device__ __forceinline__ uint32_t cvt_pk_bf16(float lo, float hi) {
  uint32_t d;
  asm("v_cvt_pk_bf16_f32 %0, %1, %2" : "=v"(d) : "v"(lo), "v"(hi));
  return d;
}

// ---- pack A: [CH/16 m_tiles][5 k_tiles][2 h][64 lane][8 j] ushorts (bf16) ----
__global__ __launch_bounds__(256) void pack_A(const float* __restrict__ z,
                                              const int* __restrict__ labels,
                                              ushort* __restrict__ Apk,
                                              int b0, int CH) {
  int idx = blockIdx.x * 256 + threadIdx.x;  // (mt,kt,h,lane)
  int lane = idx & 63;
  int h = (idx >> 6) & 1;
  int kt = (idx >> 7) % 5;
  int mt = idx / 640;
  if (mt >= CH / 16) return;
  int m = b0 + mt * 16 + (lane & 15);
  int kbase = kt * 32 + (lane >> 4) * 8;
  ushort o[8];
#pragma unroll
  for (int j = 0; j < 8; ++j) {
    int k = kbase + j;
    float v = 0.0f;
    if (k < ZFULL) v = z[(size_t)m * ZFULL + k];
    else if (k < ZFULL + NCTX) v = (float)labels[(size_t)m * NCTX + (k - ZFULL)];
    ushort hi = bf16_rne(v);
    if (h == 0) o[j] = hi;
    else {
      float fhi = __uint_as_float((uint32_t)hi << 16);
      o[j] = bf16_rne(v - fhi);
    }
  }
  uint4 w;
  w.x = (uint32_t)o[0] | ((uint32_t)o[1] << 16);
  w.y = (uint32_t)o[2] | ((uint32_t)o[3] << 16);
  w.z = (uint32_t)o[4] | ((uint32_t)o[5] << 16);
  w.w = (uint32_t)o[6] | ((uint32_t)o[7] << 16);
  *(uint4*)(Apk + (size_t)idx * 8) = w;
}

// ---- pack B: [256 n_tiles][5 k_tiles][2 h][64 lane][8 j] ushorts (bf16) ----
__global__ __launch_bounds__(256) void pack_B(const float* __restrict__ Kp,
                                              const float* __restrict__ Lm,
                                              ushort* __restrict__ Bpk) {
  int idx = blockIdx.x * 256 + threadIdx.x;
  int lane = idx & 63;
  int h = (idx >> 6) & 1;
  int kt = (idx >> 7) % 5;
  int nt = idx / 640;
  if (nt >= 256) return;
  int n = nt * 16 + (lane & 15);
  int kbase = kt * 32 + (lane >> 4) * 8;
  ushort o[8];
#pragma unroll
  for (int j = 0; j < 8; ++j) {
    int k = kbase + j;
    float v = 0.0f;
    if (k < ZFULL) v = Kp[(size_t)n * ZFULL + k];
    else if (k < ZFULL + NCTX) v = Lm[(size_t)n * NCTX + (k - ZFULL)];
    ushort hi = bf16_rne(v);
    if (h == 0) o[j] = hi;
    else {
      float fhi = __uint_as_float((uint32_t)hi << 16);
      o[j] = bf16_rne(v - fhi);
    }
  }
  uint4 w;
  w.x = (uint32_t)o[0] | ((uint32_t)o[1] << 16);
  w.y = (uint32_t)o[2] | ((uint32_t)o[3] << 16);
  w.z = (uint32_t)o[4] | ((uint32_t)o[5] << 16);
  w.w = (uint32_t)o[6] | ((uint32_t)o[7] << 16);
  *(uint4*)(Bpk + (size_t)idx * 8) = w;
}

// ---- split-bf16 MFMA GEMM -> bf16 rates (r13 form, unchanged) ----
__global__ __launch_bounds__(256) void gemm_mfma(const ushort* __restrict__ Apk,
                                                 const ushort* __restrict__ Bpk,
                                                 const float* __restrict__ base_log,
                                                 ushort* __restrict__ rates) {
  const int tid = threadIdx.x;
  const int lane = tid & 63;
  const int w = tid >> 6;
  const int wm = w & 1, wn = w >> 1;
  const int m_tile0 = blockIdx.x * 8 + wm * 4;
  const int n_tile0 = blockIdx.y * 8 + wn * 4;

  f32x4 acc[4][4] = {};

#pragma unroll
  for (int kt = 0; kt < 5; ++kt) {
    bf16x8 ah[4], al[4], bh[4], bl[4];
#pragma unroll
    for (int mt = 0; mt < 4; ++mt) {
      size_t off = (((size_t)(m_tile0 + mt) * 5 + kt) * 128 + lane) * 8;
      ah[mt] = *(const bf16x8*)(Apk + off);
      al[mt] = *(const bf16x8*)(Apk + off + 512);
    }
#pragma unroll
    for (int nt = 0; nt < 4; ++nt) {
      size_t off = (((size_t)(n_tile0 + nt) * 5 + kt) * 128 + lane) * 8;
      bh[nt] = *(const bf16x8*)(Bpk + off);
      bl[nt] = *(const bf16x8*)(Bpk + off + 512);
    }
#pragma unroll
    for (int mt = 0; mt < 4; ++mt)
#pragma unroll
      for (int nt = 0; nt < 4; ++nt) {
        acc[mt][nt] = __builtin_amdgcn_mfma_f32_16x16x32_bf16(ah[mt], bh[nt], acc[mt][nt], 0, 0, 0);
        acc[mt][nt] = __builtin_amdgcn_mfma_f32_16x16x32_bf16(ah[mt], bl[nt], acc[mt][nt], 0, 0, 0);
        acc[mt][nt] = __builtin_amdgcn_mfma_f32_16x16x32_bf16(al[mt], bh[nt], acc[mt][nt], 0, 0, 0);
      }
  }

  const int col_l = lane & 15;
  const int row_l = (lane >> 4) * 4;
  const bool evenc = (col_l & 1) == 0;
  const int r0 = evenc ? 0 : 2;
#pragma unroll
  for (int mt = 0; mt < 4; ++mt) {
#pragma unroll
    for (int nt = 0; nt < 4; ++nt) {
      int n = (n_tile0 + nt) * 16 + col_l;
      int i = n >> 6, j = n & 63;
      float bse = base_log[n];
      float x[4];
#pragma unroll
      for (int r = 0; r < 4; ++r) {
        float v = acc[mt][nt][r] + bse;
        v = fminf(fmaxf(v, -15.0f), 3.0f);
        float e = __expf(v);
        x[r] = (i == j) ? 0.0f : e;
      }
#pragma unroll
      for (int rr = 0; rr < 2; ++rr) {
        int r = r0 + rr;
        float y = __shfl_xor(x[r], 1);
        float lo = evenc ? x[r] : y;
        float hi = evenc ? y : x[r];
        uint32_t dw = cvt_pk_bf16(lo, hi);
        int m = (m_tile0 + mt) * 16 + row_l + r;
        *(uint32_t*)(rates + (size_t)m * 4096 + (n & ~1)) = dw;
      }
#pragma unroll
      for (int rr = 0; rr < 2; ++rr) {
        int r = (r0 ^ 2) + rr;
        float y = __shfl_xor(x[r], 1);
        (void)y;
      }
    }
  }
}

// ===== packed-f16 row-layout Gauss-Jordan =====
// Row held as 32 f16x2 dwords. Per step: ONE bpermute broadcasts TWO pivot
// columns; ONE v_pk_fma_f16 applies TWO column updates. Pivot-column halves
// auto-zero (a_iK - m*d_K = 0); eliminated-column garbage is never read.
// Halves the GJ issue count (r11-r14: solve is issue-count-bound; all
// broadcast mechanisms equal). Diag-dominant -> multipliers <=1, no growth.
template <int K>
struct GJ {
  static __device__ __forceinline__ void run(f16x2 (&h)[32], float& d, int lane) {
    constexpr int Q0 = K >> 1;
    f16x2 pd = bperm_h2(h[Q0], K);          // pivot row's dword holding col K
    float dk = (K & 1) ? (float)pd[1] : (float)pd[0];
    float aik = (K & 1) ? (float)h[Q0][1] : (float)h[Q0][0];
    float rp = __builtin_amdgcn_rcpf(dk);
    bool isk = (lane == K);
    float m = isk ? 0.0f : aik * rp;
    d = isk ? dk : d;
    f16x2 nm = pkrtz(-m, -m);
    h[Q0] = nm * pd + h[Q0];                // v_pk_fma_f16 (col K auto-zeroes)
#pragma unroll
    for (int q = Q0 + 1; q < 32; ++q) {
      f16x2 pq = bperm_h2(h[q], K);
      h[q] = nm * pq + h[q];
    }
    GJ<K + 1>::run(h, d, lane);
  }
};
template <>
struct GJ<63> {
  static __device__ __forceinline__ void run(f16x2 (&)[32], float&, int) {}
};

// ---- solve + attention + logits: one wave per batch (bf16 rates input) ----
__global__ __launch_bounds__(256) void solve_kernel(const ushort* __restrict__ rates,
                                                    const int* __restrict__ labels,
                                                    const float* __restrict__ Bm,
                                                    float* __restrict__ out,
                                                    int b0) {
  __shared__ float Blds[64][16];
  __shared__ float xbuf[4][64];
  __shared__ float att_lds[4][16];
  __shared__ float acc[4][80];

  const int tid = threadIdx.x;
  for (int idx = tid; idx < 1024; idx += 256)
    Blds[idx >> 4][idx & 15] = Bm[idx];

  const int wave = tid >> 6;
  const int lane = tid & 63;
  const int batch = b0 + blockIdx.x * 4 + wave;
  const ushort* Rb = rates + (size_t)(blockIdx.x * 4 + wave) * 4096;

  // ---- pass 1: cs = colsum of column `lane`, f32-accurate (diag is 0) ----
  float cs = 0.0f;
#pragma unroll
  for (int i = 0; i < 64; ++i)
    cs += __uint_as_float((uint32_t)Rb[i * 64 + lane] << 16);

  // ---- pass 2: lane holds ROW `lane` as 32 packed f16 pairs ----
  const ushort* R = Rb + (size_t)lane * 64;
  const bool is63 = (lane == 63);
  const float ncs = -cs;
  f16x2 h[32];
#pragma unroll
  for (int q = 0; q < 8; ++q) {
    uint4 u = *(const uint4*)(R + q * 8);
    uint32_t ww[4] = {u.x, u.y, u.z, u.w};
#pragma unroll
    for (int t = 0; t < 4; ++t) {
      int c0 = q * 8 + 2 * t, c1 = c0 + 1;
      float lo = __uint_as_float(ww[t] << 16);
      float hi = __uint_as_float(ww[t] & 0xFFFF0000u);
      lo = (lane == c0) ? ncs : lo;
      hi = (lane == c1) ? ncs : hi;
      lo = is63 ? 1.0f : lo;
      hi = is63 ? 1.0f : hi;
      h[q * 4 + t] = pkrtz(lo, hi);
    }
  }

  // ---- packed Gauss-Jordan pivots 0..62 (no pivoting; col-diag-dominant) ----
  float d = 1.0f;
  GJ<0>::run(h, d, lane);

  // row i<63:  d_i*x_i + a_i63*x63 = 0 ;  row 63: a_6363*x63 = 1
  float a63 = (float)h[31][1];
  float m6363 = rdlane(a63, 63);
  float x63 = 1.0f / m6363;
  float x = is63 ? x63 : -a63 * x63 * __builtin_amdgcn_rcpf(d);

  // clip >= 0 and normalize
  x = fmaxf(x, 0.0f);
  float s = x;
  s += __shfl_xor(s, 32); s += __shfl_xor(s, 16); s += __shfl_xor(s, 8);
  s += __shfl_xor(s, 4);  s += __shfl_xor(s, 2);  s += __shfl_xor(s, 1);
  x = x / s;

  xbuf[wave][lane] = x;
  if (lane < 16) {
    acc[wave][lane] = 1e-10f;
    acc[wave][16 + lane] = 1e-10f;
    acc[wave][32 + lane] = 1e-10f;
    acc[wave][48 + lane] = 1e-10f;
    acc[wave][64 + lane] = 1e-10f;
  }
  __syncthreads();

  // q[t] = p . B[:,t] for t = lane < 16
  float q = 0.0f;
  if (lane < 16) {
#pragma unroll 8
    for (int n = 0; n < 64; ++n) q = fmaf(xbuf[wave][n], Blds[n][lane], q);
  }
  float qm = q;
  qm = fmaxf(qm, __shfl_xor(qm, 8)); qm = fmaxf(qm, __shfl_xor(qm, 4));
  qm = fmaxf(qm, __shfl_xor(qm, 2)); qm = fmaxf(qm, __shfl_xor(qm, 1));
  float e = expf(q - qm);
  float es = e;
  es += __shfl_xor(es, 8); es += __shfl_xor(es, 4);
  es += __shfl_xor(es, 2); es += __shfl_xor(es, 1);
  if (lane < 16) att_lds[wave][lane] = e / es;
  __syncthreads();

  // deterministic serial bucket-accumulate (no atomics)
  if (lane == 0) {
#pragma unroll
    for (int n = 0; n < 16; ++n) {
      int lb = labels[(size_t)batch * 16 + n];
      acc[wave][lb - 1] += att_lds[wave][n];
    }
  }
  __syncthreads();

  float* ob = out + (size_t)batch * 75;
  ob[lane] = logf(acc[wave][lane]);
  if (lane < 11) ob[64 + lane] = logf(acc[wave][64 + lane]);
}

extern "C" void kernel_launch(void* const* d_in, const int* in_sizes, int n_in,
                              void* d_out, int out_size, void* d_ws, size_t ws_size,
                              hipStream_t stream) {
  const float* z      = (const float*)d_in[0];
  const int*   labels = (const int*)d_in[1];
  const float* Kp     = (const float*)d_in[2];
  const float* Lm     = (const float*)d_in[3];
  const float* Bm     = (const float*)d_in[4];
  const float* base   = (const float*)d_in[5];
  float* out = (float*)d_out;

  const int bsz = in_sizes[0] / ZFULL;  // 8192

  const size_t B_bytes = (size_t)256 * 5 * 2 * 64 * 8 * sizeof(ushort);  // 2.62 MB
  int CH = bsz;
  while (CH > 128) {
    size_t A_bytes = (size_t)(CH / 16) * 5 * 2 * 64 * 8 * sizeof(ushort);
    size_t need = B_bytes + A_bytes + (size_t)CH * 4096 * sizeof(ushort);
    if (need <= ws_size) break;
    CH >>= 1;
  }
  ushort* Bpk = (ushort*)d_ws;
  ushort* Apk = (ushort*)((char*)d_ws + B_bytes);
  size_t A_bytes = (size_t)(CH / 16) * 5 * 2 * 64 * 8 * sizeof(ushort);
  ushort* rates = (ushort*)((char*)d_ws + B_bytes + A_bytes);

  pack_B<<<(256 * 640 + 255) / 256, 256, 0, stream>>>(Kp, Lm, Bpk);

  for (int b0 = 0; b0 < bsz; b0 += CH) {
    int a_threads = (CH / 16) * 640;
    pack_A<<<(a_threads + 255) / 256, 256, 0, stream>>>(z, labels, Apk, b0, CH);
    dim3 g(CH / 128, 32);
    gemm_mfma<<<g, 256, 0, stream>>>(Apk, Bpk, base, rates);
    solve_kernel<<<CH / 4, 256, 0, stream>>>(rates, labels, Bm, out, b0);
  }
}

// Round 18
// 112.530 us; speedup vs baseline: 1.5228x; 1.0017x over previous
//
#include <hip/hip_runtime.h>
#include <cstdint>

#define ZFULL 136
#define NCTX 16
#define KCLS 75

typedef __bf16 bf16x8 __attribute__((ext_vector_type(8)));
typedef float f32x4 __attribute__((ext_vector_type(4)));
typedef _Float16 f16x2 __attribute__((ext_vector_type(2)));

__device__ __forceinline__ ushort bf16_rne(float v) {
  uint32_t u = __float_as_uint(v);
  return (ushort)((u + 0x7fffu + ((u >> 16) & 1u)) >> 16);
}

__device__ __forceinline__ float rdlane(float v, int l) {
  return __int_as_float(__builtin_amdgcn_readlane(__float_as_int(v), l));
}

__device__ __forceinline__ f16x2 bperm_h2(f16x2 v, int srcLane) {
  int i;
  __builtin_memcpy(&i, &v, 4);
  i = __builtin_amdgcn_ds_bpermute(srcLane * 4, i);
  f16x2 r;
  __builtin_memcpy(&r, &i, 4);
  return r;
}

// v_cvt_pkrtz_f16_f32 returns __fp16 vec2; bitcast to our _Float16 vec2
__device__ __forceinline__ f16x2 pkrtz(float lo, float hi) {
  auto t = __builtin_amdgcn_cvt_pkrtz(lo, hi);
  f16x2 r;
  __builtin_memcpy(&r, &t, 4);
  return r;
}

// packed bf16 convert (RNE), no builtin on gfx950 -> inline asm
__device__ __forceinline__ uint32_t cvt_pk_bf16(float lo, float hi) {
  uint32_t d;
  asm("v_cvt_pk_bf16_f32 %0, %1, %2" : "=v"(d) : "v"(lo), "v"(hi));
  return d;
}

// ---- pack A: [CH/16 m_tiles][5 k_tiles][2 h][64 lane][8 j] ushorts (bf16) ----
__global__ __launch_bounds__(256) void pack_A(const float* __restrict__ z,
                                              const int* __restrict__ labels,
                                              ushort* __restrict__ Apk,
                                              int b0, int CH) {
  int idx = blockIdx.x * 256 + threadIdx.x;  // (mt,kt,h,lane)
  int lane = idx & 63;
  int h = (idx >> 6) & 1;
  int kt = (idx >> 7) % 5;
  int mt = idx / 640;
  if (mt >= CH / 16) return;
  int m = b0 + mt * 16 + (lane & 15);
  int kbase = kt * 32 + (lane >> 4) * 8;
  ushort o[8];
#pragma unroll
  for (int j = 0; j < 8; ++j) {
    int k = kbase + j;
    float v = 0.0f;
    if (k < ZFULL) v = z[(size_t)m * ZFULL + k];
    else if (k < ZFULL + NCTX) v = (float)labels[(size_t)m * NCTX + (k - ZFULL)];
    ushort hi = bf16_rne(v);
    if (h == 0) o[j] = hi;
    else {
      float fhi = __uint_as_float((uint32_t)hi << 16);
      o[j] = bf16_rne(v - fhi);
    }
  }
  uint4 w;
  w.x = (uint32_t)o[0] | ((uint32_t)o[1] << 16);
  w.y = (uint32_t)o[2] | ((uint32_t)o[3] << 16);
  w.z = (uint32_t)o[4] | ((uint32_t)o[5] << 16);
  w.w = (uint32_t)o[6] | ((uint32_t)o[7] << 16);
  *(uint4*)(Apk + (size_t)idx * 8) = w;
}

// ---- pack B: [256 n_tiles][5 k_tiles][2 h][64 lane][8 j] ushorts (bf16) ----
__global__ __launch_bounds__(256) void pack_B(const float* __restrict__ Kp,
                                              const float* __restrict__ Lm,
                                              ushort* __restrict__ Bpk) {
  int idx = blockIdx.x * 256 + threadIdx.x;
  int lane = idx & 63;
  int h = (idx >> 6) & 1;
  int kt = (idx >> 7) % 5;
  int nt = idx / 640;
  if (nt >= 256) return;
  int n = nt * 16 + (lane & 15);
  int kbase = kt * 32 + (lane >> 4) * 8;
  ushort o[8];
#pragma unroll
  for (int j = 0; j < 8; ++j) {
    int k = kbase + j;
    float v = 0.0f;
    if (k < ZFULL) v = Kp[(size_t)n * ZFULL + k];
    else if (k < ZFULL + NCTX) v = Lm[(size_t)n * NCTX + (k - ZFULL)];
    ushort hi = bf16_rne(v);
    if (h == 0) o[j] = hi;
    else {
      float fhi = __uint_as_float((uint32_t)hi << 16);
      o[j] = bf16_rne(v - fhi);
    }
  }
  uint4 w;
  w.x = (uint32_t)o[0] | ((uint32_t)o[1] << 16);
  w.y = (uint32_t)o[2] | ((uint32_t)o[3] << 16);
  w.z = (uint32_t)o[4] | ((uint32_t)o[5] << 16);
  w.w = (uint32_t)o[6] | ((uint32_t)o[7] << 16);
  *(uint4*)(Bpk + (size_t)idx * 8) = w;
}

// ---- split-bf16 MFMA GEMM -> bf16 rates (r13 form, unchanged) ----
__global__ __launch_bounds__(256) void gemm_mfma(const ushort* __restrict__ Apk,
                                                 const ushort* __restrict__ Bpk,
                                                 const float* __restrict__ base_log,
                                                 ushort* __restrict__ rates) {
  const int tid = threadIdx.x;
  const int lane = tid & 63;
  const int w = tid >> 6;
  const int wm = w & 1, wn = w >> 1;
  const int m_tile0 = blockIdx.x * 8 + wm * 4;
  const int n_tile0 = blockIdx.y * 8 + wn * 4;

  f32x4 acc[4][4] = {};

#pragma unroll
  for (int kt = 0; kt < 5; ++kt) {
    bf16x8 ah[4], al[4], bh[4], bl[4];
#pragma unroll
    for (int mt = 0; mt < 4; ++mt) {
      size_t off = (((size_t)(m_tile0 + mt) * 5 + kt) * 128 + lane) * 8;
      ah[mt] = *(const bf16x8*)(Apk + off);
      al[mt] = *(const bf16x8*)(Apk + off + 512);
    }
#pragma unroll
    for (int nt = 0; nt < 4; ++nt) {
      size_t off = (((size_t)(n_tile0 + nt) * 5 + kt) * 128 + lane) * 8;
      bh[nt] = *(const bf16x8*)(Bpk + off);
      bl[nt] = *(const bf16x8*)(Bpk + off + 512);
    }
#pragma unroll
    for (int mt = 0; mt < 4; ++mt)
#pragma unroll
      for (int nt = 0; nt < 4; ++nt) {
        acc[mt][nt] = __builtin_amdgcn_mfma_f32_16x16x32_bf16(ah[mt], bh[nt], acc[mt][nt], 0, 0, 0);
        acc[mt][nt] = __builtin_amdgcn_mfma_f32_16x16x32_bf16(ah[mt], bl[nt], acc[mt][nt], 0, 0, 0);
        acc[mt][nt] = __builtin_amdgcn_mfma_f32_16x16x32_bf16(al[mt], bh[nt], acc[mt][nt], 0, 0, 0);
      }
  }

  const int col_l = lane & 15;
  const int row_l = (lane >> 4) * 4;
  const bool evenc = (col_l & 1) == 0;
  const int r0 = evenc ? 0 : 2;
#pragma unroll
  for (int mt = 0; mt < 4; ++mt) {
#pragma unroll
    for (int nt = 0; nt < 4; ++nt) {
      int n = (n_tile0 + nt) * 16 + col_l;
      int i = n >> 6, j = n & 63;
      float bse = base_log[n];
      float x[4];
#pragma unroll
      for (int r = 0; r < 4; ++r) {
        float v = acc[mt][nt][r] + bse;
        v = fminf(fmaxf(v, -15.0f), 3.0f);
        float e = __expf(v);
        x[r] = (i == j) ? 0.0f : e;
      }
#pragma unroll
      for (int rr = 0; rr < 2; ++rr) {
        int r = r0 + rr;
        float y = __shfl_xor(x[r], 1);
        float lo = evenc ? x[r] : y;
        float hi = evenc ? y : x[r];
        uint32_t dw = cvt_pk_bf16(lo, hi);
        int m = (m_tile0 + mt) * 16 + row_l + r;
        *(uint32_t*)(rates + (size_t)m * 4096 + (n & ~1)) = dw;
      }
#pragma unroll
      for (int rr = 0; rr < 2; ++rr) {
        int r = (r0 ^ 2) + rr;
        float y = __shfl_xor(x[r], 1);
        (void)y;
      }
    }
  }
}

// ===== packed-f16 Gauss-Jordan with software-pipelined pivot broadcast =====
// Step K receives its pivot dword pd (prefetched in step K-1). The NEXT pivot
// dword (K even: same dword Q0; K odd: dword Q0+1) is updated FIRST and its
// bpermute issued immediately, so the ~50-cycle broadcast latency hides under
// the remaining ~30 independent pk_fma pairs instead of serializing the step
// heads (r17: serial head ~80cy x 63 steps was the post-packing residue).
template <int K>
struct GJ {
  static __device__ __forceinline__ void run(f16x2 (&h)[32], f16x2 pd, float& d,
                                             float& m63, int lane) {
    constexpr int Q0 = K >> 1;
    float dk = (K & 1) ? (float)pd[1] : (float)pd[0];
    float aik = (K & 1) ? (float)h[Q0][1] : (float)h[Q0][0];
    float rp = __builtin_amdgcn_rcpf(dk);
    bool isk = (lane == K);
    float m = isk ? 0.0f : aik * rp;
    d = isk ? dk : d;
    f16x2 nm = pkrtz(-m, -m);
    h[Q0] = nm * pd + h[Q0];  // pivot dword updates first (col K auto-zeroes)
    f16x2 pdn;
    if constexpr ((K & 1) == 0) {
      pdn = bperm_h2(h[Q0], K + 1);  // next pivot = other half of same dword
#pragma unroll
      for (int q = Q0 + 1; q < 32; ++q) {
        f16x2 pq = bperm_h2(h[q], K);
        h[q] = nm * pq + h[q];
      }
    } else {
      f16x2 pq1 = bperm_h2(h[Q0 + 1], K);
      h[Q0 + 1] = nm * pq1 + h[Q0 + 1];
      pdn = bperm_h2(h[Q0 + 1], K + 1);  // next pivot dword, just updated
#pragma unroll
      for (int q = Q0 + 2; q < 32; ++q) {
        f16x2 pq = bperm_h2(h[q], K);
        h[q] = nm * pq + h[q];
      }
    }
    GJ<K + 1>::run(h, pdn, d, m63, lane);
  }
};
template <>
struct GJ<63> {
  static __device__ __forceinline__ void run(f16x2 (&)[32], f16x2 pd, float&,
                                             float& m63, int) {
    m63 = (float)pd[1];  // bperm(h[31],63)[1] == M[63][63] broadcast (free)
  }
};

// ---- solve + attention + logits: one wave per batch (bf16 rates input) ----
__global__ __launch_bounds__(256) void solve_kernel(const ushort* __restrict__ rates,
                                                    const int* __restrict__ labels,
                                                    const float* __restrict__ Bm,
                                                    float* __restrict__ out,
                                                    int b0) {
  __shared__ float Blds[64][16];
  __shared__ float xbuf[4][64];
  __shared__ float att_lds[4][16];
  __shared__ float acc[4][80];

  const int tid = threadIdx.x;
  for (int idx = tid; idx < 1024; idx += 256)
    Blds[idx >> 4][idx & 15] = Bm[idx];

  const int wave = tid >> 6;
  const int lane = tid & 63;
  const int batch = b0 + blockIdx.x * 4 + wave;
  const ushort* Rb = rates + (size_t)(blockIdx.x * 4 + wave) * 4096;

  // ---- pass 1: cs = colsum of column `lane`, f32-accurate (diag is 0) ----
  float cs = 0.0f;
#pragma unroll
  for (int i = 0; i < 64; ++i)
    cs += __uint_as_float((uint32_t)Rb[i * 64 + lane] << 16);

  // ---- pass 2: lane holds ROW `lane` as 32 packed f16 pairs ----
  const ushort* R = Rb + (size_t)lane * 64;
  const bool is63 = (lane == 63);
  const float ncs = -cs;
  f16x2 h[32];
#pragma unroll
  for (int q = 0; q < 8; ++q) {
    uint4 u = *(const uint4*)(R + q * 8);
    uint32_t ww[4] = {u.x, u.y, u.z, u.w};
#pragma unroll
    for (int t = 0; t < 4; ++t) {
      int c0 = q * 8 + 2 * t, c1 = c0 + 1;
      float lo = __uint_as_float(ww[t] << 16);
      float hi = __uint_as_float(ww[t] & 0xFFFF0000u);
      lo = (lane == c0) ? ncs : lo;
      hi = (lane == c1) ? ncs : hi;
      lo = is63 ? 1.0f : lo;
      hi = is63 ? 1.0f : hi;
      h[q * 4 + t] = pkrtz(lo, hi);
    }
  }

  // ---- pipelined packed Gauss-Jordan pivots 0..62 ----
  float d = 1.0f, m6363 = 1.0f;
  f16x2 pd0 = bperm_h2(h[0], 0);
  GJ<0>::run(h, pd0, d, m6363, lane);

  // row i<63:  d_i*x_i + a_i63*x63 = 0 ;  row 63: a_6363*x63 = 1
  float a63 = (float)h[31][1];
  float x63 = 1.0f / m6363;
  float x = is63 ? x63 : -a63 * x63 * __builtin_amdgcn_rcpf(d);

  // clip >= 0 and normalize
  x = fmaxf(x, 0.0f);
  float s = x;
  s += __shfl_xor(s, 32); s += __shfl_xor(s, 16); s += __shfl_xor(s, 8);
  s += __shfl_xor(s, 4);  s += __shfl_xor(s, 2);  s += __shfl_xor(s, 1);
  x = x / s;

  xbuf[wave][lane] = x;
  if (lane < 16) {
    acc[wave][lane] = 1e-10f;
    acc[wave][16 + lane] = 1e-10f;
    acc[wave][32 + lane] = 1e-10f;
    acc[wave][48 + lane] = 1e-10f;
    acc[wave][64 + lane] = 1e-10f;
  }
  __syncthreads();

  // q[t] = p . B[:,t] for t = lane < 16
  float q = 0.0f;
  if (lane < 16) {
#pragma unroll 8
    for (int n = 0; n < 64; ++n) q = fmaf(xbuf[wave][n], Blds[n][lane], q);
  }
  float qm = q;
  qm = fmaxf(qm, __shfl_xor(qm, 8)); qm = fmaxf(qm, __shfl_xor(qm, 4));
  qm = fmaxf(qm, __shfl_xor(qm, 2)); qm = fmaxf(qm, __shfl_xor(qm, 1));
  float e = expf(q - qm);
  float es = e;
  es += __shfl_xor(es, 8); es += __shfl_xor(es, 4);
  es += __shfl_xor(es, 2); es += __shfl_xor(es, 1);
  if (lane < 16) att_lds[wave][lane] = e / es;
  __syncthreads();

  // deterministic serial bucket-accumulate (no atomics)
  if (lane == 0) {
#pragma unroll
    for (int n = 0; n < 16; ++n) {
      int lb = labels[(size_t)batch * 16 + n];
      acc[wave][lb - 1] += att_lds[wave][n];
    }
  }
  __syncthreads();

  float* ob = out + (size_t)batch * 75;
  ob[lane] = logf(acc[wave][lane]);
  if (lane < 11) ob[64 + lane] = logf(acc[wave][64 + lane]);
}

extern "C" void kernel_launch(void* const* d_in, const int* in_sizes, int n_in,
                              void* d_out, int out_size, void* d_ws, size_t ws_size,
                              hipStream_t stream) {
  const float* z      = (const float*)d_in[0];
  const int*   labels = (const int*)d_in[1];
  const float* Kp     = (const float*)d_in[2];
  const float* Lm     = (const float*)d_in[3];
  const float* Bm     = (const float*)d_in[4];
  const float* base   = (const float*)d_in[5];
  float* out = (float*)d_out;

  const int bsz = in_sizes[0] / ZFULL;  // 8192

  const size_t B_bytes = (size_t)256 * 5 * 2 * 64 * 8 * sizeof(ushort);  // 2.62 MB
  int CH = bsz;
  while (CH > 128) {
    size_t A_bytes = (size_t)(CH / 16) * 5 * 2 * 64 * 8 * sizeof(ushort);
    size_t need = B_bytes + A_bytes + (size_t)CH * 4096 * sizeof(ushort);
    if (need <= ws_size) break;
    CH >>= 1;
  }
  ushort* Bpk = (ushort*)d_ws;
  ushort* Apk = (ushort*)((char*)d_ws + B_bytes);
  size_t A_bytes = (size_t)(CH / 16) * 5 * 2 * 64 * 8 * sizeof(ushort);
  ushort* rates = (ushort*)((char*)d_ws + B_bytes + A_bytes);

  pack_B<<<(256 * 640 + 255) / 256, 256, 0, stream>>>(Kp, Lm, Bpk);

  for (int b0 = 0; b0 < bsz; b0 += CH) {
    int a_threads = (CH / 16) * 640;
    pack_A<<<(a_threads + 255) / 256, 256, 0, stream>>>(z, labels, Apk, b0, CH);
    dim3 g(CH / 128, 32);
    gemm_mfma<<<g, 256, 0, stream>>>(Apk, Bpk, base, rates);
    solve_kernel<<<CH / 4, 256, 0, stream>>>(rates, labels, Bm, out, b0);
  }
}

// Round 19
// 94.949 us; speedup vs baseline: 1.8048x; 1.1852x over previous
//
#include <hip/hip_runtime.h>
#include <cstdint>

#define ZFULL 136
#define NCTX 16
#define KCLS 75

typedef __bf16 bf16x8 __attribute__((ext_vector_type(8)));
typedef float f32x4 __attribute__((ext_vector_type(4)));
typedef _Float16 f16x2 __attribute__((ext_vector_type(2)));

__device__ __forceinline__ ushort bf16_rne(float v) {
  uint32_t u = __float_as_uint(v);
  return (ushort)((u + 0x7fffu + ((u >> 16) & 1u)) >> 16);
}

__device__ __forceinline__ float rdlane(float v, int l) {
  return __int_as_float(__builtin_amdgcn_readlane(__float_as_int(v), l));
}

__device__ __forceinline__ f16x2 bperm_h2(f16x2 v, int srcLane) {
  int i;
  __builtin_memcpy(&i, &v, 4);
  i = __builtin_amdgcn_ds_bpermute(srcLane * 4, i);
  f16x2 r;
  __builtin_memcpy(&r, &i, 4);
  return r;
}

// v_cvt_pkrtz_f16_f32 returns __fp16 vec2; bitcast to our _Float16 vec2
__device__ __forceinline__ f16x2 pkrtz(float lo, float hi) {
  auto t = __builtin_amdgcn_cvt_pkrtz(lo, hi);
  f16x2 r;
  __builtin_memcpy(&r, &t, 4);
  return r;
}

// packed bf16 convert (RNE), no builtin on gfx950 -> inline asm
__device__ __forceinline__ uint32_t cvt_pk_bf16(float lo, float hi) {
  uint32_t d;
  asm("v_cvt_pk_bf16_f32 %0, %1, %2" : "=v"(d) : "v"(lo), "v"(hi));
  return d;
}

// ---- pack A: [CH/16 m_tiles][5 k_tiles][2 h][64 lane][8 j] ushorts (bf16) ----
__global__ __launch_bounds__(256) void pack_A(const float* __restrict__ z,
                                              const int* __restrict__ labels,
                                              ushort* __restrict__ Apk,
                                              int b0, int CH) {
  int idx = blockIdx.x * 256 + threadIdx.x;  // (mt,kt,h,lane)
  int lane = idx & 63;
  int h = (idx >> 6) & 1;
  int kt = (idx >> 7) % 5;
  int mt = idx / 640;
  if (mt >= CH / 16) return;
  int m = b0 + mt * 16 + (lane & 15);
  int kbase = kt * 32 + (lane >> 4) * 8;
  ushort o[8];
#pragma unroll
  for (int j = 0; j < 8; ++j) {
    int k = kbase + j;
    float v = 0.0f;
    if (k < ZFULL) v = z[(size_t)m * ZFULL + k];
    else if (k < ZFULL + NCTX) v = (float)labels[(size_t)m * NCTX + (k - ZFULL)];
    ushort hi = bf16_rne(v);
    if (h == 0) o[j] = hi;
    else {
      float fhi = __uint_as_float((uint32_t)hi << 16);
      o[j] = bf16_rne(v - fhi);
    }
  }
  uint4 w;
  w.x = (uint32_t)o[0] | ((uint32_t)o[1] << 16);
  w.y = (uint32_t)o[2] | ((uint32_t)o[3] << 16);
  w.z = (uint32_t)o[4] | ((uint32_t)o[5] << 16);
  w.w = (uint32_t)o[6] | ((uint32_t)o[7] << 16);
  *(uint4*)(Apk + (size_t)idx * 8) = w;
}

// ---- pack B: [256 n_tiles][5 k_tiles][2 h][64 lane][8 j] ushorts (bf16) ----
__global__ __launch_bounds__(256) void pack_B(const float* __restrict__ Kp,
                                              const float* __restrict__ Lm,
                                              ushort* __restrict__ Bpk) {
  int idx = blockIdx.x * 256 + threadIdx.x;
  int lane = idx & 63;
  int h = (idx >> 6) & 1;
  int kt = (idx >> 7) % 5;
  int nt = idx / 640;
  if (nt >= 256) return;
  int n = nt * 16 + (lane & 15);
  int kbase = kt * 32 + (lane >> 4) * 8;
  ushort o[8];
#pragma unroll
  for (int j = 0; j < 8; ++j) {
    int k = kbase + j;
    float v = 0.0f;
    if (k < ZFULL) v = Kp[(size_t)n * ZFULL + k];
    else if (k < ZFULL + NCTX) v = Lm[(size_t)n * NCTX + (k - ZFULL)];
    ushort hi = bf16_rne(v);
    if (h == 0) o[j] = hi;
    else {
      float fhi = __uint_as_float((uint32_t)hi << 16);
      o[j] = bf16_rne(v - fhi);
    }
  }
  uint4 w;
  w.x = (uint32_t)o[0] | ((uint32_t)o[1] << 16);
  w.y = (uint32_t)o[2] | ((uint32_t)o[3] << 16);
  w.z = (uint32_t)o[4] | ((uint32_t)o[5] << 16);
  w.w = (uint32_t)o[6] | ((uint32_t)o[7] << 16);
  *(uint4*)(Bpk + (size_t)idx * 8) = w;
}

// ---- bf16 MFMA GEMM (1-term: Ah*Bh) -> bf16 rates ----
// r19: absmax stayed 0.015625 from full-f32 GEMM (r1) through split-bf16
// (r2-r18) -> output error is downstream-dominated; the split's 2^-17 was
// wasted. Pure bf16 gives rates rel-err ~0.3% -> logits delta ~0.01 << 0.46.
// 80 MFMA + 40 loads per wave vs 240 + 80. Epilogue identical to r18.
__global__ __launch_bounds__(256) void gemm_mfma(const ushort* __restrict__ Apk,
                                                 const ushort* __restrict__ Bpk,
                                                 const float* __restrict__ base_log,
                                                 ushort* __restrict__ rates) {
  const int tid = threadIdx.x;
  const int lane = tid & 63;
  const int w = tid >> 6;
  const int wm = w & 1, wn = w >> 1;
  const int m_tile0 = blockIdx.x * 8 + wm * 4;
  const int n_tile0 = blockIdx.y * 8 + wn * 4;

  f32x4 acc[4][4] = {};

#pragma unroll
  for (int kt = 0; kt < 5; ++kt) {
    bf16x8 ah[4], bh[4];
#pragma unroll
    for (int mt = 0; mt < 4; ++mt) {
      size_t off = (((size_t)(m_tile0 + mt) * 5 + kt) * 128 + lane) * 8;
      ah[mt] = *(const bf16x8*)(Apk + off);
    }
#pragma unroll
    for (int nt = 0; nt < 4; ++nt) {
      size_t off = (((size_t)(n_tile0 + nt) * 5 + kt) * 128 + lane) * 8;
      bh[nt] = *(const bf16x8*)(Bpk + off);
    }
#pragma unroll
    for (int mt = 0; mt < 4; ++mt)
#pragma unroll
      for (int nt = 0; nt < 4; ++nt)
        acc[mt][nt] = __builtin_amdgcn_mfma_f32_16x16x32_bf16(ah[mt], bh[nt], acc[mt][nt], 0, 0, 0);
  }

  const int col_l = lane & 15;
  const int row_l = (lane >> 4) * 4;
  const bool evenc = (col_l & 1) == 0;
  const int r0 = evenc ? 0 : 2;
#pragma unroll
  for (int mt = 0; mt < 4; ++mt) {
#pragma unroll
    for (int nt = 0; nt < 4; ++nt) {
      int n = (n_tile0 + nt) * 16 + col_l;
      int i = n >> 6, j = n & 63;
      float bse = base_log[n];
      float x[4];
#pragma unroll
      for (int r = 0; r < 4; ++r) {
        float v = acc[mt][nt][r] + bse;
        v = fminf(fmaxf(v, -15.0f), 3.0f);
        float e = __expf(v);
        x[r] = (i == j) ? 0.0f : e;
      }
#pragma unroll
      for (int rr = 0; rr < 2; ++rr) {
        int r = r0 + rr;
        float y = __shfl_xor(x[r], 1);
        float lo = evenc ? x[r] : y;
        float hi = evenc ? y : x[r];
        uint32_t dw = cvt_pk_bf16(lo, hi);
        int m = (m_tile0 + mt) * 16 + row_l + r;
        *(uint32_t*)(rates + (size_t)m * 4096 + (n & ~1)) = dw;
      }
#pragma unroll
      for (int rr = 0; rr < 2; ++rr) {
        int r = (r0 ^ 2) + rr;
        float y = __shfl_xor(x[r], 1);
        (void)y;
      }
    }
  }
}

// ===== packed-f16 Gauss-Jordan with software-pipelined pivot broadcast =====
template <int K>
struct GJ {
  static __device__ __forceinline__ void run(f16x2 (&h)[32], f16x2 pd, float& d,
                                             float& m63, int lane) {
    constexpr int Q0 = K >> 1;
    float dk = (K & 1) ? (float)pd[1] : (float)pd[0];
    float aik = (K & 1) ? (float)h[Q0][1] : (float)h[Q0][0];
    float rp = __builtin_amdgcn_rcpf(dk);
    bool isk = (lane == K);
    float m = isk ? 0.0f : aik * rp;
    d = isk ? dk : d;
    f16x2 nm = pkrtz(-m, -m);
    h[Q0] = nm * pd + h[Q0];  // pivot dword updates first (col K auto-zeroes)
    f16x2 pdn;
    if constexpr ((K & 1) == 0) {
      pdn = bperm_h2(h[Q0], K + 1);  // next pivot = other half of same dword
#pragma unroll
      for (int q = Q0 + 1; q < 32; ++q) {
        f16x2 pq = bperm_h2(h[q], K);
        h[q] = nm * pq + h[q];
      }
    } else {
      f16x2 pq1 = bperm_h2(h[Q0 + 1], K);
      h[Q0 + 1] = nm * pq1 + h[Q0 + 1];
      pdn = bperm_h2(h[Q0 + 1], K + 1);  // next pivot dword, just updated
#pragma unroll
      for (int q = Q0 + 2; q < 32; ++q) {
        f16x2 pq = bperm_h2(h[q], K);
        h[q] = nm * pq + h[q];
      }
    }
    GJ<K + 1>::run(h, pdn, d, m63, lane);
  }
};
template <>
struct GJ<63> {
  static __device__ __forceinline__ void run(f16x2 (&)[32], f16x2 pd, float&,
                                             float& m63, int) {
    m63 = (float)pd[1];  // bperm(h[31],63)[1] == M[63][63] broadcast (free)
  }
};

// ---- solve + attention + logits: one wave per batch (bf16 rates input) ----
__global__ __launch_bounds__(256) void solve_kernel(const ushort* __restrict__ rates,
                                                    const int* __restrict__ labels,
                                                    const float* __restrict__ Bm,
                                                    float* __restrict__ out,
                                                    int b0) {
  __shared__ float Blds[64][16];
  __shared__ float xbuf[4][64];
  __shared__ float att_lds[4][16];
  __shared__ float acc[4][80];

  const int tid = threadIdx.x;
  for (int idx = tid; idx < 1024; idx += 256)
    Blds[idx >> 4][idx & 15] = Bm[idx];

  const int wave = tid >> 6;
  const int lane = tid & 63;
  const int batch = b0 + blockIdx.x * 4 + wave;
  const ushort* Rb = rates + (size_t)(blockIdx.x * 4 + wave) * 4096;

  // ---- pass 1: cs = colsum of column `lane`, f32-accurate (diag is 0) ----
  float cs = 0.0f;
#pragma unroll
  for (int i = 0; i < 64; ++i)
    cs += __uint_as_float((uint32_t)Rb[i * 64 + lane] << 16);

  // ---- pass 2: lane holds ROW `lane` as 32 packed f16 pairs ----
  const ushort* R = Rb + (size_t)lane * 64;
  const bool is63 = (lane == 63);
  const float ncs = -cs;
  f16x2 h[32];
#pragma unroll
  for (int q = 0; q < 8; ++q) {
    uint4 u = *(const uint4*)(R + q * 8);
    uint32_t ww[4] = {u.x, u.y, u.z, u.w};
#pragma unroll
    for (int t = 0; t < 4; ++t) {
      int c0 = q * 8 + 2 * t, c1 = c0 + 1;
      float lo = __uint_as_float(ww[t] << 16);
      float hi = __uint_as_float(ww[t] & 0xFFFF0000u);
      lo = (lane == c0) ? ncs : lo;
      hi = (lane == c1) ? ncs : hi;
      lo = is63 ? 1.0f : lo;
      hi = is63 ? 1.0f : hi;
      h[q * 4 + t] = pkrtz(lo, hi);
    }
  }

  // ---- pipelined packed Gauss-Jordan pivots 0..62 ----
  float d = 1.0f, m6363 = 1.0f;
  f16x2 pd0 = bperm_h2(h[0], 0);
  GJ<0>::run(h, pd0, d, m6363, lane);

  // row i<63:  d_i*x_i + a_i63*x63 = 0 ;  row 63: a_6363*x63 = 1
  float a63 = (float)h[31][1];
  float x63 = 1.0f / m6363;
  float x = is63 ? x63 : -a63 * x63 * __builtin_amdgcn_rcpf(d);

  // clip >= 0 and normalize
  x = fmaxf(x, 0.0f);
  float s = x;
  s += __shfl_xor(s, 32); s += __shfl_xor(s, 16); s += __shfl_xor(s, 8);
  s += __shfl_xor(s, 4);  s += __shfl_xor(s, 2);  s += __shfl_xor(s, 1);
  x = x / s;

  xbuf[wave][lane] = x;
  if (lane < 16) {
    acc[wave][lane] = 1e-10f;
    acc[wave][16 + lane] = 1e-10f;
    acc[wave][32 + lane] = 1e-10f;
    acc[wave][48 + lane] = 1e-10f;
    acc[wave][64 + lane] = 1e-10f;
  }
  __syncthreads();

  // q[t] = p . B[:,t] for t = lane < 16
  float q = 0.0f;
  if (lane < 16) {
#pragma unroll 8
    for (int n = 0; n < 64; ++n) q = fmaf(xbuf[wave][n], Blds[n][lane], q);
  }
  float qm = q;
  qm = fmaxf(qm, __shfl_xor(qm, 8)); qm = fmaxf(qm, __shfl_xor(qm, 4));
  qm = fmaxf(qm, __shfl_xor(qm, 2)); qm = fmaxf(qm, __shfl_xor(qm, 1));
  float e = expf(q - qm);
  float es = e;
  es += __shfl_xor(es, 8); es += __shfl_xor(es, 4);
  es += __shfl_xor(es, 2); es += __shfl_xor(es, 1);
  if (lane < 16) att_lds[wave][lane] = e / es;
  __syncthreads();

  // deterministic serial bucket-accumulate (no atomics)
  if (lane == 0) {
#pragma unroll
    for (int n = 0; n < 16; ++n) {
      int lb = labels[(size_t)batch * 16 + n];
      acc[wave][lb - 1] += att_lds[wave][n];
    }
  }
  __syncthreads();

  float* ob = out + (size_t)batch * 75;
  ob[lane] = logf(acc[wave][lane]);
  if (lane < 11) ob[64 + lane] = logf(acc[wave][64 + lane]);
}

extern "C" void kernel_launch(void* const* d_in, const int* in_sizes, int n_in,
                              void* d_out, int out_size, void* d_ws, size_t ws_size,
                              hipStream_t stream) {
  const float* z      = (const float*)d_in[0];
  const int*   labels = (const int*)d_in[1];
  const float* Kp     = (const float*)d_in[2];
  const float* Lm     = (const float*)d_in[3];
  const float* Bm     = (const float*)d_in[4];
  const float* base   = (const float*)d_in[5];
  float* out = (float*)d_out;

  const int bsz = in_sizes[0] / ZFULL;  // 8192

  const size_t B_bytes = (size_t)256 * 5 * 2 * 64 * 8 * sizeof(ushort);  // 2.62 MB
  int CH = bsz;
  while (CH > 128) {
    size_t A_bytes = (size_t)(CH / 16) * 5 * 2 * 64 * 8 * sizeof(ushort);
    size_t need = B_bytes + A_bytes + (size_t)CH * 4096 * sizeof(ushort);
    if (need <= ws_size) break;
    CH >>= 1;
  }
  ushort* Bpk = (ushort*)d_ws;
  ushort* Apk = (ushort*)((char*)d_ws + B_bytes);
  size_t A_bytes = (size_t)(CH / 16) * 5 * 2 * 64 * 8 * sizeof(ushort);
  ushort* rates = (ushort*)((char*)d_ws + B_bytes + A_bytes);

  pack_B<<<(256 * 640 + 255) / 256, 256, 0, stream>>>(Kp, Lm, Bpk);

  for (int b0 = 0; b0 < bsz; b0 += CH) {
    int a_threads = (CH / 16) * 640;
    pack_A<<<(a_threads + 255) / 256, 256, 0, stream>>>(z, labels, Apk, b0, CH);
    dim3 g(CH / 128, 32);
    gemm_mfma<<<g, 256, 0, stream>>>(Apk, Bpk, base, rates);
    solve_kernel<<<CH / 4, 256, 0, stream>>>(rates, labels, Bm, out, b0);
  }
}